// Round 8
// baseline (174.601 us; speedup 1.0000x reference)
//
#include <hip/hip_runtime.h>
#include <cstdint>

namespace {
constexpr int NWIN = 4096;
constexpr int NT   = 49;
constexpr int D    = 128;
constexpr float SCALE = 0.17677669529663687f;  // 1/sqrt(32)

constexpr int SQ = 136;   // LDS row stride (ushorts) token-major buffers
constexpr int SV = 72;    // LDS row stride for V^T (fallback kernel)

// wbuf layout (ushort element offsets)
constexpr size_t WQH   = 0;       // qkv_w hi frags (Q cols pre-scaled): 24nt*4ks*64*8 = 49152
constexpr size_t WOH   = 49152;   // wo_w hi frags: 8nt*4ks*64*8 = 16384
constexpr size_t WOL   = 65536;   // wo_w lo frags: 16384
constexpr size_t BFRAG = 81920;   // bias frags: 16 pairs * 64 lanes * 16 = 16384
constexpr size_t WBUF_BYTES = 98304 * 2;

// split-path QKV intermediate in d_ws, after wbuf
constexpr size_t QKV_OFF_USH = 98304;          // ushort offset of window 0
constexpr int    WIN_USH     = 24576;          // per window: Q 8192, K 8192, Vfrag 8192
constexpr size_t TOTAL_WS_BYTES = WBUF_BYTES + (size_t)NWIN * WIN_USH * 2;  // ~192.2 MB
}

using short8 = __attribute__((ext_vector_type(8))) short;
using f32x4  = __attribute__((ext_vector_type(4))) float;

__device__ __forceinline__ ushort f2bf(float x) {           // round-to-nearest-even
    uint u = __builtin_bit_cast(uint, x);
    uint r = u + 0x7FFFu + ((u >> 16) & 1u);
    return (ushort)(r >> 16);
}
__device__ __forceinline__ ushort f2bf_tr(float x) {        // truncate (damped paths)
    return (ushort)(__builtin_bit_cast(uint, x) >> 16);
}
__device__ __forceinline__ float bf2f(ushort b) {
    uint u = ((uint)b) << 16;
    return __builtin_bit_cast(float, u);
}

// ---------------- prep: weight frags + bias frags (unchanged) ----------------
__global__ __launch_bounds__(256) void prep_all(
    const float* __restrict__ qkv_w, const float* __restrict__ wo_w,
    const float* __restrict__ bias_table, const int* __restrict__ bias_index,
    ushort* __restrict__ wbuf)
{
    const int blk = blockIdx.x, tid = threadIdx.x;
    if (blk < 96) {
        const int nt = blk >> 2, ks = blk & 3;
        for (int e = tid; e < 512; e += 256) {
            const int lane = e >> 3, j = e & 7;
            const int k = ks * 32 + (lane >> 4) * 8 + j;
            const int n = nt * 16 + (lane & 15);
            float wv = qkv_w[(size_t)k * 384 + n];
            if (n < 128) wv *= SCALE;
            wbuf[WQH + ((size_t)(nt * 4 + ks) * 64 + lane) * 8 + j] = f2bf(wv);
        }
    } else if (blk < 128) {
        const int b2 = blk - 96;
        const int nt = b2 >> 2, ks = b2 & 3;
        for (int e = tid; e < 512; e += 256) {
            const int lane = e >> 3, j = e & 7;
            const int k = ks * 32 + (lane >> 4) * 8 + j;
            const int n = nt * 16 + (lane & 15);
            const float wv = wo_w[(size_t)k * 128 + n];
            const ushort h = f2bf(wv);
            const size_t fo = ((size_t)(nt * 4 + ks) * 64 + lane) * 8 + j;
            wbuf[WOH + fo] = h;
            wbuf[WOL + fo] = f2bf(wv - bf2f(h));
        }
    } else {
        const int p = blk - 128;
        const int h = p >> 2, qt = p & 3;
        for (int ei = tid; ei < 1024; ei += 256) {
            const int lane = ei >> 4, t = (ei >> 2) & 3, r = ei & 3;
            const int q = qt * 16 + (lane & 15);
            const int k = 16 * t + 4 * (lane >> 4) + r;
            float v = 0.f;
            if (q < NT && k < NT) v = bias_table[bias_index[q * NT + k] * 4 + h];
            wbuf[BFRAG + (size_t)p * 1024 + ei] = f2bf(v);
        }
    }
}

// ---------------- K1: QKV projection, one window per block ----------------
// Writes per window (ushort): Q [64][128] trunc-bf16 pre-scaled at +0,
// K [64][128] trunc at +8192, V as 16 MFMA frags (h,dt,ks) at +16384 with
// sigma-permuted token slots: frag word (lane=(g,lr), j) holds
// V[token=32ks+16(j>>2)+4g+(j&3)][d=h*32+dt*16+lr].
__global__ __launch_bounds__(512, 4) void qkv_gemm(
    const float* __restrict__ x, const float* __restrict__ qkv_b,
    const ushort* __restrict__ wbuf, ushort* __restrict__ qkvg)
{
    __shared__ __align__(16) ushort s_x[64 * SQ];

    const int b = blockIdx.x, tid = threadIdx.x;
    const int wid = tid >> 6, lane = tid & 63;
    const int g = lane >> 4, lr = lane & 15;
    const float* xb = x + (size_t)b * NT * D;

    // stage x (RNE bf16), zero pad rows
    for (int i = tid; i < 15 * SQ; i += 512) s_x[49 * SQ + i] = 0;
    for (int i = tid; i < NT * 32; i += 512) {
        const int r = i >> 5, c4 = (i & 31) * 4;
        const float4 v = *reinterpret_cast<const float4*>(&xb[r * D + c4]);
        ushort4 hv;
        hv.x = f2bf(v.x); hv.y = f2bf(v.y);
        hv.z = f2bf(v.z); hv.w = f2bf(v.w);
        *reinterpret_cast<ushort4*>(&s_x[r * SQ + c4]) = hv;
    }
    __syncthreads();

    const int mp  = wid & 1;     // m in {2mp, 2mp+1}
    const int ntb = (wid >> 1) * 6;

    short8 Ax[2][4];
    #pragma unroll
    for (int mi = 0; mi < 2; ++mi)
        #pragma unroll
        for (int ks = 0; ks < 4; ++ks)
            Ax[mi][ks] = *reinterpret_cast<const short8*>(
                &s_x[((2 * mp + mi) * 16 + lr) * SQ + ks * 32 + g * 8]);

    float qb[6];
    #pragma unroll
    for (int i = 0; i < 6; ++i) {
        const int nt = ntb + i;
        float v = qkv_b[nt * 16 + lr];
        if (nt < 8) v *= SCALE;
        qb[i] = v;
    }

    f32x4 acc[2][6] = {};
    #pragma unroll
    for (int ks = 0; ks < 4; ++ks) {
        short8 Bf[6];
        #pragma unroll
        for (int i = 0; i < 6; ++i)
            Bf[i] = *reinterpret_cast<const short8*>(
                &wbuf[WQH + ((size_t)((ntb + i) * 4 + ks) * 64 + lane) * 8]);
        #pragma unroll
        for (int i = 0; i < 6; ++i) {
            acc[0][i] = __builtin_amdgcn_mfma_f32_16x16x32_bf16(Ax[0][ks], Bf[i], acc[0][i], 0, 0, 0);
            acc[1][i] = __builtin_amdgcn_mfma_f32_16x16x32_bf16(Ax[1][ks], Bf[i], acc[1][i], 0, 0, 0);
        }
    }

    ushort* const wq = qkvg + (size_t)b * WIN_USH;
    #pragma unroll
    for (int i = 0; i < 6; ++i) {
        const int nt = ntb + i;
        const int n = nt * 16 + lr;
        #pragma unroll
        for (int mi = 0; mi < 2; ++mi) {
            const int m = 2 * mp + mi;
            if (nt < 16) {
                ushort* const dst = (nt < 8) ? wq : (wq + 8192);
                const int col = n & 127;
                #pragma unroll
                for (int jj = 0; jj < 4; ++jj)
                    dst[(m * 16 + 4 * g + jj) * 128 + col] = f2bf_tr(acc[mi][i][jj] + qb[i]);
            } else {
                const int d  = n - 256;
                const int f  = (((d >> 5) * 2 + ((d >> 4) & 1)) * 2) + (m >> 1);
                const int j0 = 4 * (m & 1);
                ushort4 hv;
                #pragma unroll
                for (int jj = 0; jj < 4; ++jj)
                    (&hv.x)[jj] = f2bf(acc[mi][i][jj] + qb[i]);   // RNE (un-damped)
                *reinterpret_cast<ushort4*>(&wq[16384 + ((size_t)f * 64 + lane) * 8 + j0]) = hv;
            }
        }
    }
}

// ---------------- K2: attention + out-proj, one window per block ----------------
// LDS = attn-out only (34.8 KB); exactly one barrier.
__global__ __launch_bounds__(512, 4) void attn_out(
    const ushort* __restrict__ qkvg, const ushort* __restrict__ wbuf,
    const float* __restrict__ wo_b, float* __restrict__ out)
{
    __shared__ __align__(16) ushort s_o[64 * SQ];

    const int b = blockIdx.x, tid = threadIdx.x;
    const int wid = tid >> 6, lane = tid & 63;
    const int g = lane >> 4, lr = lane & 15;
    const ushort* const wq = qkvg + (size_t)b * WIN_USH;
    const ushort* const wk = wq + 8192;
    const ushort* const wv = wq + 16384;

    // wave w handles pairs with h = w>>1, qt = (w&1)*2 + pi  (halves K/V re-reads)
    const int h = wid >> 1;
    short8 pa[2][2];
    float inv2[2];
    #pragma unroll
    for (int pi = 0; pi < 2; ++pi) {
        const int qt = (wid & 1) * 2 + pi;
        const int p  = h * 4 + qt;

        const short8 Qf = *reinterpret_cast<const short8*>(&wq[(qt * 16 + lr) * 128 + h * 32 + g * 8]);
        f32x4 sc[4];
        #pragma unroll
        for (int t = 0; t < 4; ++t) {
            const short8 Kf = *reinterpret_cast<const short8*>(&wk[(t * 16 + lr) * 128 + h * 32 + g * 8]);
            f32x4 z = {};
            sc[t] = __builtin_amdgcn_mfma_f32_16x16x32_bf16(Kf, Qf, z, 0, 0, 0);
        }
        uint bw[8];
        {
            const uint4 b0 = *reinterpret_cast<const uint4*>(&wbuf[BFRAG + ((size_t)p * 64 + lane) * 16]);
            const uint4 b1 = *reinterpret_cast<const uint4*>(&wbuf[BFRAG + ((size_t)p * 64 + lane) * 16 + 8]);
            bw[0] = b0.x; bw[1] = b0.y; bw[2] = b0.z; bw[3] = b0.w;
            bw[4] = b1.x; bw[5] = b1.y; bw[6] = b1.z; bw[7] = b1.w;
        }
        // exp, trunc to bf16, sum of ROUNDED values (trunc bias cancels in normalize)
        float lsum = 0.f;
        uint pw[8];
        #pragma unroll
        for (int t = 0; t < 4; ++t) {
            float ebits[4];
            #pragma unroll
            for (int r = 0; r < 4; ++r) {
                const int idx = 4 * t + r;
                const uint bwv = bw[idx >> 1];
                const float bv = __builtin_bit_cast(float, (idx & 1) ? (bwv & 0xFFFF0000u) : (bwv << 16));
                float e;
                if (t < 3) {
                    e = __expf(sc[t][r] + bv);
                } else if (r == 0) {
                    e = (g == 0) ? __expf(sc[t][0] + bv) : 0.f;   // k=48 only
                } else {
                    e = 0.f;
                }
                const uint tr = __builtin_bit_cast(uint, e) & 0xFFFF0000u;
                ebits[r] = __builtin_bit_cast(float, tr);
                lsum += ebits[r];
            }
            pw[t * 2 + 0] = (__builtin_bit_cast(uint, ebits[0]) >> 16) | (__builtin_bit_cast(uint, ebits[1]) & 0xFFFF0000u);
            pw[t * 2 + 1] = (__builtin_bit_cast(uint, ebits[2]) >> 16) | (__builtin_bit_cast(uint, ebits[3]) & 0xFFFF0000u);
        }
        lsum += __shfl_xor(lsum, 16);
        lsum += __shfl_xor(lsum, 32);
        inv2[pi] = 1.f / lsum;
        #pragma unroll
        for (int ks = 0; ks < 2; ++ks) {
            uint4 w;
            w.x = pw[(2 * ks) * 2 + 0]; w.y = pw[(2 * ks) * 2 + 1];
            w.z = pw[(2 * ks + 1) * 2 + 0]; w.w = pw[(2 * ks + 1) * 2 + 1];
            pa[pi][ks] = __builtin_bit_cast(short8, w);
        }
    }

    // PV: V frags straight from global (coalesced 16B/lane)
    f32x4 oac[2][2];
    #pragma unroll
    for (int pi = 0; pi < 2; ++pi) {
        #pragma unroll
        for (int dt = 0; dt < 2; ++dt) {
            f32x4 o = {};
            #pragma unroll
            for (int ks = 0; ks < 2; ++ks) {
                const int f = ((h * 2 + dt) * 2) + ks;
                const short8 Vf = *reinterpret_cast<const short8*>(&wv[((size_t)f * 64 + lane) * 8]);
                o = __builtin_amdgcn_mfma_f32_16x16x32_bf16(pa[pi][ks], Vf, o, 0, 0, 0);
            }
            oac[pi][dt] = o;
        }
    }
    // normalize -> attn-out into LDS
    #pragma unroll
    for (int pi = 0; pi < 2; ++pi) {
        const int qt = (wid & 1) * 2 + pi;
        #pragma unroll
        for (int dt = 0; dt < 2; ++dt) {
            const int d = h * 32 + dt * 16 + lr;
            #pragma unroll
            for (int r = 0; r < 4; ++r) {
                const float inv = __shfl(inv2[pi], 4 * g + r);
                const int q = qt * 16 + 4 * g + r;
                s_o[q * SQ + d] = f2bf(oac[pi][dt][r] * inv);   // RNE
            }
        }
    }
    __syncthreads();   // the ONE barrier

    // out-proj: wave owns nt = wid; all 4 token-quarters
    {
        const int nt = wid;
        const float wb = wo_b[nt * 16 + lr];
        f32x4 acc[4] = {};
        #pragma unroll
        for (int ks = 0; ks < 4; ++ks) {
            const size_t fo = ((size_t)(nt * 4 + ks) * 64 + lane) * 8;
            const short8 Wh = *reinterpret_cast<const short8*>(&wbuf[WOH + fo]);
            const short8 Wl = *reinterpret_cast<const short8*>(&wbuf[WOL + fo]);
            #pragma unroll
            for (int m = 0; m < 4; ++m) {
                const short8 Ah = *reinterpret_cast<const short8*>(&s_o[(m * 16 + lr) * SQ + ks * 32 + g * 8]);
                acc[m] = __builtin_amdgcn_mfma_f32_16x16x32_bf16(Ah, Wh, acc[m], 0, 0, 0);
                acc[m] = __builtin_amdgcn_mfma_f32_16x16x32_bf16(Ah, Wl, acc[m], 0, 0, 0);
            }
        }
        float* ob = out + (size_t)b * NT * D;
        #pragma unroll
        for (int m = 0; m < 4; ++m) {
            #pragma unroll
            for (int jj = 0; jj < 4; ++jj) {
                const int q = m * 16 + 4 * g + jj;
                if (q < NT) ob[q * D + nt * 16 + lr] = acc[m][jj] + wb;
            }
        }
    }
}

// ---------------- fallback: R6 fused kernel (proven 166 us) ----------------
template <bool PREPPED>
__global__ __launch_bounds__(512, 4) void win_attn(
    const float* __restrict__ x,
    const float* __restrict__ qkv_w, const float* __restrict__ qkv_b,
    const float* __restrict__ wo_w,  const float* __restrict__ wo_b,
    const float* __restrict__ bias_table, const int* __restrict__ bias_index,
    const ushort* __restrict__ wbuf, float* __restrict__ out)
{
    __shared__ __align__(16) ushort s_all[26624];
    ushort* const s_qh = s_all;
    ushort* const s_kh = s_all + 8704;
    ushort* const s_vt = s_all + 17408;

    const int b = blockIdx.x, tid = threadIdx.x;
    const int wid = tid >> 6, lane = tid & 63;
    const int g = lane >> 4, lr = lane & 15;
    const int m = wid >> 1;
    const int nt0 = (wid & 1) * 12;
    const float* xb = x + (size_t)b * NT * D;

    short8 Ax[4];
    {
        const int row = m * 16 + lr;
        if (row < NT) {
            const float* xr = xb + row * D;
            #pragma unroll
            for (int ks = 0; ks < 4; ++ks) {
                const float4 v0 = *reinterpret_cast<const float4*>(&xr[ks * 32 + g * 8]);
                const float4 v1 = *reinterpret_cast<const float4*>(&xr[ks * 32 + g * 8 + 4]);
                uint4 w;
                w.x = ((uint)f2bf(v0.x)) | (((uint)f2bf(v0.y)) << 16);
                w.y = ((uint)f2bf(v0.z)) | (((uint)f2bf(v0.w)) << 16);
                w.z = ((uint)f2bf(v1.x)) | (((uint)f2bf(v1.y)) << 16);
                w.w = ((uint)f2bf(v1.z)) | (((uint)f2bf(v1.w)) << 16);
                Ax[ks] = __builtin_bit_cast(short8, w);
            }
        } else {
            #pragma unroll
            for (int ks = 0; ks < 4; ++ks) Ax[ks] = short8{0,0,0,0,0,0,0,0};
        }
    }
    float qb[12];
    #pragma unroll
    for (int i = 0; i < 12; ++i) {
        const int nt = nt0 + i;
        float v = qkv_b[nt * 16 + lr];
        if (nt < 8) v *= SCALE;
        qb[i] = v;
    }

    #pragma unroll
    for (int pass = 0; pass < 2; ++pass) {
        const int ntb = nt0 + pass * 6;
        short8 Bs[2][6];
        f32x4 acc[6] = {};
        #pragma unroll
        for (int i = 0; i < 6; ++i) {
            if constexpr (PREPPED) {
                Bs[0][i] = *reinterpret_cast<const short8*>(
                    &wbuf[WQH + ((size_t)((ntb + i) * 4 + 0) * 64 + lane) * 8]);
            } else {
                #pragma unroll
                for (int j = 0; j < 8; ++j) {
                    float wv = qkv_w[(size_t)(g * 8 + j) * 384 + (ntb + i) * 16 + lr];
                    if (ntb + i < 8) wv *= SCALE;
                    Bs[0][i][j] = (short)f2bf(wv);
                }
            }
        }
        #pragma unroll
        for (int ks = 0; ks < 4; ++ks) {
            const int cur = ks & 1, nxt = cur ^ 1;
            if (ks < 3) {
                #pragma unroll
                for (int i = 0; i < 6; ++i) {
                    if constexpr (PREPPED) {
                        Bs[nxt][i] = *reinterpret_cast<const short8*>(
                            &wbuf[WQH + ((size_t)((ntb + i) * 4 + ks + 1) * 64 + lane) * 8]);
                    } else {
                        #pragma unroll
                        for (int j = 0; j < 8; ++j) {
                            float wv = qkv_w[(size_t)((ks + 1) * 32 + g * 8 + j) * 384 + (ntb + i) * 16 + lr];
                            if (ntb + i < 8) wv *= SCALE;
                            Bs[nxt][i][j] = (short)f2bf(wv);
                        }
                    }
                }
            }
            #pragma unroll
            for (int i = 0; i < 6; ++i)
                acc[i] = __builtin_amdgcn_mfma_f32_16x16x32_bf16(Ax[ks], Bs[cur][i], acc[i], 0, 0, 0);
        }
        #pragma unroll
        for (int i = 0; i < 6; ++i) {
            const int nt = ntb + i;
            const int n = nt * 16 + lr;
            const float bias = qb[pass * 6 + i];
            if (nt < 16) {
                ushort* const dst = (nt < 8) ? s_qh : s_kh;
                const int col = n & 127;
                #pragma unroll
                for (int jj = 0; jj < 4; ++jj) {
                    const int q = m * 16 + g * 4 + jj;
                    dst[q * SQ + col] = f2bf_tr(acc[i][jj] + bias);
                }
            } else {
                const int d = n - 256;
                const int cbase = 32 * (m >> 1) + 8 * ((4 * m + g) & 3) + 4 * (m & 1);
                ushort4 hv;
                #pragma unroll
                for (int jj = 0; jj < 4; ++jj)
                    (&hv.x)[jj] = f2bf(acc[i][jj] + bias);
                *reinterpret_cast<ushort4*>(&s_vt[d * SV + cbase]) = hv;
            }
        }
    }
    __syncthreads();

    {
        short8 pa[2][2];
        float inv2[2];
        #pragma unroll
        for (int pi = 0; pi < 2; ++pi) {
            const int p = wid * 2 + pi;
            const int h = p >> 2, qt = p & 3;
            uint bw[8];
            if constexpr (PREPPED) {
                const uint4 b0 = *reinterpret_cast<const uint4*>(&wbuf[BFRAG + ((size_t)p * 64 + lane) * 16]);
                const uint4 b1 = *reinterpret_cast<const uint4*>(&wbuf[BFRAG + ((size_t)p * 64 + lane) * 16 + 8]);
                bw[0] = b0.x; bw[1] = b0.y; bw[2] = b0.z; bw[3] = b0.w;
                bw[4] = b1.x; bw[5] = b1.y; bw[6] = b1.z; bw[7] = b1.w;
            } else {
                const int q = qt * 16 + lr;
                #pragma unroll
                for (int t = 0; t < 4; ++t) {
                    #pragma unroll
                    for (int r = 0; r < 4; r += 2) {
                        const int k0 = 16 * t + 4 * g + r, k1 = k0 + 1;
                        float v0 = 0.f, v1 = 0.f;
                        if (q < NT && k0 < NT) v0 = bias_table[bias_index[q * NT + k0] * 4 + h];
                        if (q < NT && k1 < NT) v1 = bias_table[bias_index[q * NT + k1] * 4 + h];
                        bw[(4 * t + r) >> 1] = ((uint)f2bf(v0)) | (((uint)f2bf(v1)) << 16);
                    }
                }
            }
            const short8 Qf = *reinterpret_cast<const short8*>(&s_qh[(qt * 16 + lr) * SQ + h * 32 + g * 8]);
            f32x4 sc[4];
            #pragma unroll
            for (int t = 0; t < 4; ++t) {
                const short8 Kf = *reinterpret_cast<const short8*>(&s_kh[(t * 16 + lr) * SQ + h * 32 + g * 8]);
                f32x4 z = {};
                sc[t] = __builtin_amdgcn_mfma_f32_16x16x32_bf16(Kf, Qf, z, 0, 0, 0);
            }
            float lsum = 0.f;
            uint pw[8];
            #pragma unroll
            for (int t = 0; t < 4; ++t) {
                float ebits[4];
                #pragma unroll
                for (int r = 0; r < 4; ++r) {
                    const int idx = 4 * t + r;
                    const uint bwv = bw[idx >> 1];
                    const float bv = __builtin_bit_cast(float, (idx & 1) ? (bwv & 0xFFFF0000u) : (bwv << 16));
                    float e;
                    if (t < 3) {
                        e = __expf(sc[t][r] + bv);
                    } else if (r == 0) {
                        e = (g == 0) ? __expf(sc[t][0] + bv) : 0.f;
                    } else {
                        e = 0.f;
                    }
                    const uint tr = __builtin_bit_cast(uint, e) & 0xFFFF0000u;
                    ebits[r] = __builtin_bit_cast(float, tr);
                    lsum += ebits[r];
                }
                pw[t * 2 + 0] = (__builtin_bit_cast(uint, ebits[0]) >> 16) | (__builtin_bit_cast(uint, ebits[1]) & 0xFFFF0000u);
                pw[t * 2 + 1] = (__builtin_bit_cast(uint, ebits[2]) >> 16) | (__builtin_bit_cast(uint, ebits[3]) & 0xFFFF0000u);
            }
            lsum += __shfl_xor(lsum, 16);
            lsum += __shfl_xor(lsum, 32);
            inv2[pi] = 1.f / lsum;
            #pragma unroll
            for (int ks = 0; ks < 2; ++ks) {
                uint4 w;
                w.x = pw[(2 * ks) * 2 + 0]; w.y = pw[(2 * ks) * 2 + 1];
                w.z = pw[(2 * ks + 1) * 2 + 0]; w.w = pw[(2 * ks + 1) * 2 + 1];
                pa[pi][ks] = __builtin_bit_cast(short8, w);
            }
        }

        f32x4 oac[2][2];
        #pragma unroll
        for (int pi = 0; pi < 2; ++pi) {
            const int p = wid * 2 + pi;
            const int h = p >> 2;
            #pragma unroll
            for (int dt = 0; dt < 2; ++dt) {
                f32x4 o = {};
                #pragma unroll
                for (int ks = 0; ks < 2; ++ks) {
                    const short8 Vf = *reinterpret_cast<const short8*>(&s_vt[(h * 32 + dt * 16 + lr) * SV + ks * 32 + g * 8]);
                    o = __builtin_amdgcn_mfma_f32_16x16x32_bf16(pa[pi][ks], Vf, o, 0, 0, 0);
                }
                oac[pi][dt] = o;
            }
        }
        __syncthreads();

        #pragma unroll
        for (int pi = 0; pi < 2; ++pi) {
            const int p = wid * 2 + pi;
            const int h = p >> 2, qt = p & 3;
            #pragma unroll
            for (int dt = 0; dt < 2; ++dt) {
                const int d = h * 32 + dt * 16 + lr;
                #pragma unroll
                for (int r = 0; r < 4; ++r) {
                    const float inv = __shfl(inv2[pi], 4 * g + r);
                    const int q = qt * 16 + 4 * g + r;
                    s_qh[q * SQ + d] = f2bf(oac[pi][dt][r] * inv);
                }
            }
        }
    }
    __syncthreads();

    {
        const int nt04 = (wid & 1) * 4;
        float wb4[4];
        #pragma unroll
        for (int i = 0; i < 4; ++i) wb4[i] = wo_b[(nt04 + i) * 16 + lr];

        short8 Wh[2][4], Wl[2][4];
        f32x4 acc[4] = {};
        #pragma unroll
        for (int i = 0; i < 4; ++i) {
            if constexpr (PREPPED) {
                const size_t fo = ((size_t)((nt04 + i) * 4 + 0) * 64 + lane) * 8;
                Wh[0][i] = *reinterpret_cast<const short8*>(&wbuf[WOH + fo]);
                Wl[0][i] = *reinterpret_cast<const short8*>(&wbuf[WOL + fo]);
            } else {
                #pragma unroll
                for (int j = 0; j < 8; ++j) {
                    const float wv = wo_w[(size_t)(g * 8 + j) * 128 + (nt04 + i) * 16 + lr];
                    const ushort hh = f2bf(wv);
                    Wh[0][i][j] = (short)hh;
                    Wl[0][i][j] = (short)f2bf(wv - bf2f(hh));
                }
            }
        }
        #pragma unroll
        for (int ks = 0; ks < 4; ++ks) {
            const int cur = ks & 1, nxt = cur ^ 1;
            if (ks < 3) {
                #pragma unroll
                for (int i = 0; i < 4; ++i) {
                    if constexpr (PREPPED) {
                        const size_t fo = ((size_t)((nt04 + i) * 4 + ks + 1) * 64 + lane) * 8;
                        Wh[nxt][i] = *reinterpret_cast<const short8*>(&wbuf[WOH + fo]);
                        Wl[nxt][i] = *reinterpret_cast<const short8*>(&wbuf[WOL + fo]);
                    } else {
                        #pragma unroll
                        for (int j = 0; j < 8; ++j) {
                            const float wv = wo_w[(size_t)((ks + 1) * 32 + g * 8 + j) * 128 + (nt04 + i) * 16 + lr];
                            const ushort hh = f2bf(wv);
                            Wh[nxt][i][j] = (short)hh;
                            Wl[nxt][i][j] = (short)f2bf(wv - bf2f(hh));
                        }
                    }
                }
            }
            const short8 Ah = *reinterpret_cast<const short8*>(&s_qh[(m * 16 + lr) * SQ + ks * 32 + g * 8]);
            #pragma unroll
            for (int i = 0; i < 4; ++i) {
                acc[i] = __builtin_amdgcn_mfma_f32_16x16x32_bf16(Ah, Wh[cur][i], acc[i], 0, 0, 0);
                acc[i] = __builtin_amdgcn_mfma_f32_16x16x32_bf16(Ah, Wl[cur][i], acc[i], 0, 0, 0);
            }
        }
        float* ob = out + (size_t)b * NT * D;
        #pragma unroll
        for (int i = 0; i < 4; ++i) {
            const int n = (nt04 + i) * 16 + lr;
            #pragma unroll
            for (int jj = 0; jj < 4; ++jj) {
                const int q = m * 16 + g * 4 + jj;
                if (q < NT) ob[q * D + n] = acc[i][jj] + wb4[i];
            }
        }
    }
}

extern "C" void kernel_launch(void* const* d_in, const int* in_sizes, int n_in,
                              void* d_out, int out_size, void* d_ws, size_t ws_size,
                              hipStream_t stream) {
    const float* x          = (const float*)d_in[0];
    const float* qkv_w      = (const float*)d_in[1];
    const float* qkv_b      = (const float*)d_in[2];
    const float* wo_w       = (const float*)d_in[3];
    const float* wo_b       = (const float*)d_in[4];
    const float* bias_table = (const float*)d_in[5];
    const int*   bias_index = (const int*)d_in[6];
    float* outp = (float*)d_out;

    if (ws_size >= TOTAL_WS_BYTES) {
        ushort* wbuf = (ushort*)d_ws;
        ushort* qkvg = wbuf + QKV_OFF_USH;
        prep_all<<<dim3(144), dim3(256), 0, stream>>>(qkv_w, wo_w, bias_table, bias_index, wbuf);
        qkv_gemm<<<dim3(NWIN), dim3(512), 0, stream>>>(x, qkv_b, wbuf, qkvg);
        attn_out<<<dim3(NWIN), dim3(512), 0, stream>>>(qkvg, wbuf, wo_b, outp);
    } else if (ws_size >= WBUF_BYTES) {
        ushort* wbuf = (ushort*)d_ws;
        prep_all<<<dim3(144), dim3(256), 0, stream>>>(qkv_w, wo_w, bias_table, bias_index, wbuf);
        win_attn<true><<<dim3(NWIN), dim3(512), 0, stream>>>(
            x, qkv_w, qkv_b, wo_w, wo_b, bias_table, bias_index, wbuf, outp);
    } else {
        win_attn<false><<<dim3(NWIN), dim3(512), 0, stream>>>(
            x, qkv_w, qkv_b, wo_w, wo_b, bias_table, bias_index, nullptr, outp);
    }
}